// Round 1
// baseline (3639.543 us; speedup 1.0000x reference)
//
#include <hip/hip_runtime.h>
#include <hip/hip_bf16.h>
#include <cstdint>
#include <cstddef>

#define T_TOK  4096
#define HID    2048
#define NEXP   32
#define NROUTE 48
#define IDIM   1024
#define TOPK   6
#define RSCALE 2.5f

// GEMM tiling
#define TM  128
#define TN  64
#define BK  64
#define LDT 88   // LDS row stride (bf16 elems): 64 + 24 pad -> 176B rows, 16B aligned, conflict-friendly

typedef __attribute__((ext_vector_type(8))) __bf16 bf16x8;
typedef __attribute__((ext_vector_type(4))) float f32x4;
typedef __attribute__((ext_vector_type(8))) unsigned short us8;

static __device__ __forceinline__ unsigned short f2bf(float f) {
  unsigned u = __builtin_bit_cast(unsigned, f);
  u += 0x7fffu + ((u >> 16) & 1u);          // round-to-nearest-even
  return (unsigned short)(u >> 16);
}

// ---------------- kernel: x fp32 -> bf16 ----------------
__global__ void k_cvt_x(const float* __restrict__ x, unsigned short* __restrict__ xb) {
  int i = blockIdx.x * blockDim.x + threadIdx.x;   // one thread = 8 elems
  const float4* xv = (const float4*)x;
  float4 a = xv[2 * i], b = xv[2 * i + 1];
  us8 p;
  p[0] = f2bf(a.x); p[1] = f2bf(a.y); p[2] = f2bf(a.z); p[3] = f2bf(a.w);
  p[4] = f2bf(b.x); p[5] = f2bf(b.y); p[6] = f2bf(b.z); p[7] = f2bf(b.w);
  *(us8*)(xb + 8 * (size_t)i) = p;
}

// ---------------- kernel: router (fp32) + top-6 + expert lists ----------------
__global__ __launch_bounds__(256) void k_router(
    const float* __restrict__ x, const float* __restrict__ rw,
    const float* __restrict__ cb, float* __restrict__ zw_out,
    int* __restrict__ counts, int* __restrict__ ltok, float* __restrict__ lw)
{
  __shared__ float xs[16][132];
  __shared__ float wsm[48][132];
  __shared__ float sc[16][48];
  __shared__ float cbs[48];
  const int tid = threadIdx.x;
  const int t0 = blockIdx.x * 16;
  if (tid < NROUTE) cbs[tid] = cb[tid];
  const int tl = tid & 15, eg = tid >> 4;
  const int e0 = eg * 3;
  float a0 = 0.f, a1 = 0.f, a2 = 0.f;

  for (int hb = 0; hb < HID; hb += 128) {
    {
      int r = tid >> 4, c = (tid & 15) * 8;
      const float4* s = (const float4*)(x + (size_t)(t0 + r) * HID + hb + c);
      *(float4*)&xs[r][c]     = s[0];
      *(float4*)&xs[r][c + 4] = s[1];
    }
#pragma unroll
    for (int j = 0; j < 3; ++j) {
      int L = tid * 8 + j * 2048;
      int r = L >> 7, c = L & 127;
      const float4* s = (const float4*)(rw + (size_t)r * HID + hb + c);
      *(float4*)&wsm[r][c]     = s[0];
      *(float4*)&wsm[r][c + 4] = s[1];
    }
    __syncthreads();
#pragma unroll 8
    for (int h = 0; h < 128; h += 4) {
      float4 xv = *(const float4*)&xs[tl][h];
      float4 w0 = *(const float4*)&wsm[e0][h];
      float4 w1v = *(const float4*)&wsm[e0 + 1][h];
      float4 w2v = *(const float4*)&wsm[e0 + 2][h];
      a0 += xv.x * w0.x + xv.y * w0.y + xv.z * w0.z + xv.w * w0.w;
      a1 += xv.x * w1v.x + xv.y * w1v.y + xv.z * w1v.z + xv.w * w1v.w;
      a2 += xv.x * w2v.x + xv.y * w2v.y + xv.z * w2v.z + xv.w * w2v.w;
    }
    __syncthreads();
  }
  sc[tl][e0]     = 1.f / (1.f + expf(-a0));
  sc[tl][e0 + 1] = 1.f / (1.f + expf(-a1));
  sc[tl][e0 + 2] = 1.f / (1.f + expf(-a2));
  __syncthreads();

  if (tid < 16) {
    int t = t0 + tid;
    unsigned long long used = 0ull;
    float wsum = 0.f, zwv = 0.f;
    int   re[TOPK];  float rwt[TOPK];  int nr = 0;
#pragma unroll
    for (int k = 0; k < TOPK; ++k) {
      float best = -1e30f; int bi = 0;
      for (int e = 0; e < NROUTE; ++e) {
        if ((used >> e) & 1ull) continue;
        float v = sc[tid][e] + cbs[e];
        if (v > best) { best = v; bi = e; }   // strict > keeps lowest index on ties (lax.top_k)
      }
      used |= 1ull << bi;
      float w = sc[tid][bi];
      wsum += w;
      if (bi >= NEXP) zwv += w;
      else { re[nr] = bi; rwt[nr] = w; ++nr; }
    }
    float scale = RSCALE / wsum;
    zw_out[t] = zwv * scale;
    for (int j = 0; j < nr; ++j) {
      int e = re[j];
      int p = atomicAdd(&counts[e], 1);
      ltok[e * T_TOK + p] = t;
      lw[e * T_TOK + p]   = rwt[j] * scale;
    }
  }
}

// ---------------- kernel: exclusive scan of counts ----------------
__global__ void k_scan(const int* __restrict__ counts, int* __restrict__ offsets) {
  if (threadIdx.x == 0) {
    int o = 0;
    for (int e = 0; e < NEXP; ++e) { offsets[e] = o; o += counts[e]; }
  }
}

// ---------------- kernel: grouped GEMM gate+up + SiLU, act out (bf16) ----------------
__global__ __launch_bounds__(256, 2) void k_gate_up(
    const unsigned short* __restrict__ xb, const float* __restrict__ w1,
    const float* __restrict__ w3, const int* __restrict__ counts,
    const int* __restrict__ offsets, const int* __restrict__ ltok,
    unsigned short* __restrict__ act)
{
  const int e   = blockIdx.z;
  const int cnt = counts[e];
  const int m0  = blockIdx.x * TM;
  if (m0 >= cnt) return;
  const int nb  = blockIdx.y * TN;
  const int off = offsets[e];

  __shared__ unsigned short As[TM * LDT];
  __shared__ unsigned short W1s[TN * LDT];
  __shared__ unsigned short W3s[TN * LDT];

  const int tid  = threadIdx.x;
  const int lane = tid & 63, wid = tid >> 6;
  const int wm = wid & 1, wn = wid >> 1;
  const int quad = lane >> 4, l15 = lane & 15;

  // A staging map: 8 threads per row, 4 rows per thread
  const int ar = tid >> 3;            // 0..31
  const int ac = (tid & 7) * 8;       // 0..56
  int tokr[4];
#pragma unroll
  for (int r4 = 0; r4 < 4; ++r4) {
    int mr = m0 + ar + 32 * r4;
    tokr[r4] = (mr < cnt) ? ltok[e * T_TOK + mr] : 0;
  }
  // W staging map: 4 threads per row (16 fp32 each)
  const int wr = tid >> 2;            // 0..63
  const int wc = (tid & 3) * 16;      // 0..48
  const float* w1p = w1 + ((size_t)e * IDIM + (nb + wr)) * HID + wc;
  const float* w3p = w3 + ((size_t)e * IDIM + (nb + wr)) * HID + wc;

  f32x4 accg[4][2], accu[4][2];
#pragma unroll
  for (int mt = 0; mt < 4; ++mt)
#pragma unroll
    for (int nt = 0; nt < 2; ++nt) { accg[mt][nt] = (f32x4)0.f; accu[mt][nt] = (f32x4)0.f; }

  for (int kb = 0; kb < HID; kb += BK) {
    us8 av[4];
#pragma unroll
    for (int r4 = 0; r4 < 4; ++r4)
      av[r4] = *(const us8*)(xb + (size_t)tokr[r4] * HID + kb + ac);
    float4 v1a = *(const float4*)(w1p + kb),     v1b = *(const float4*)(w1p + kb + 4);
    float4 v1c = *(const float4*)(w1p + kb + 8), v1d = *(const float4*)(w1p + kb + 12);
    float4 v3a = *(const float4*)(w3p + kb),     v3b = *(const float4*)(w3p + kb + 4);
    float4 v3c = *(const float4*)(w3p + kb + 8), v3d = *(const float4*)(w3p + kb + 12);

    __syncthreads();
#pragma unroll
    for (int r4 = 0; r4 < 4; ++r4)
      *(us8*)&As[(ar + 32 * r4) * LDT + ac] = av[r4];
    {
      us8 q0, q1;
      q0[0]=f2bf(v1a.x); q0[1]=f2bf(v1a.y); q0[2]=f2bf(v1a.z); q0[3]=f2bf(v1a.w);
      q0[4]=f2bf(v1b.x); q0[5]=f2bf(v1b.y); q0[6]=f2bf(v1b.z); q0[7]=f2bf(v1b.w);
      q1[0]=f2bf(v1c.x); q1[1]=f2bf(v1c.y); q1[2]=f2bf(v1c.z); q1[3]=f2bf(v1c.w);
      q1[4]=f2bf(v1d.x); q1[5]=f2bf(v1d.y); q1[6]=f2bf(v1d.z); q1[7]=f2bf(v1d.w);
      *(us8*)&W1s[wr * LDT + wc] = q0;
      *(us8*)&W1s[wr * LDT + wc + 8] = q1;
      q0[0]=f2bf(v3a.x); q0[1]=f2bf(v3a.y); q0[2]=f2bf(v3a.z); q0[3]=f2bf(v3a.w);
      q0[4]=f2bf(v3b.x); q0[5]=f2bf(v3b.y); q0[6]=f2bf(v3b.z); q0[7]=f2bf(v3b.w);
      q1[0]=f2bf(v3c.x); q1[1]=f2bf(v3c.y); q1[2]=f2bf(v3c.z); q1[3]=f2bf(v3c.w);
      q1[4]=f2bf(v3d.x); q1[5]=f2bf(v3d.y); q1[6]=f2bf(v3d.z); q1[7]=f2bf(v3d.w);
      *(us8*)&W3s[wr * LDT + wc] = q0;
      *(us8*)&W3s[wr * LDT + wc + 8] = q1;
    }
    __syncthreads();

#pragma unroll
    for (int ks = 0; ks < 2; ++ks) {
      bf16x8 af[4];
#pragma unroll
      for (int mt = 0; mt < 4; ++mt)
        af[mt] = *(const bf16x8*)&As[(wm * 64 + mt * 16 + l15) * LDT + ks * 32 + quad * 8];
      bf16x8 b1f[2], b3f[2];
#pragma unroll
      for (int nt = 0; nt < 2; ++nt) {
        b1f[nt] = *(const bf16x8*)&W1s[(wn * 32 + nt * 16 + l15) * LDT + ks * 32 + quad * 8];
        b3f[nt] = *(const bf16x8*)&W3s[(wn * 32 + nt * 16 + l15) * LDT + ks * 32 + quad * 8];
      }
#pragma unroll
      for (int mt = 0; mt < 4; ++mt)
#pragma unroll
        for (int nt = 0; nt < 2; ++nt) {
          accg[mt][nt] = __builtin_amdgcn_mfma_f32_16x16x32_bf16(af[mt], b1f[nt], accg[mt][nt], 0, 0, 0);
          accu[mt][nt] = __builtin_amdgcn_mfma_f32_16x16x32_bf16(af[mt], b3f[nt], accu[mt][nt], 0, 0, 0);
        }
    }
  }

#pragma unroll
  for (int mt = 0; mt < 4; ++mt)
#pragma unroll
    for (int nt = 0; nt < 2; ++nt) {
      int icol = nb + wn * 32 + nt * 16 + l15;
#pragma unroll
      for (int r = 0; r < 4; ++r) {
        int mrow = m0 + wm * 64 + mt * 16 + quad * 4 + r;
        if (mrow < cnt) {
          float g = accg[mt][nt][r], u = accu[mt][nt][r];
          float sv = g / (1.f + expf(-g)) * u;      // silu(g)*u
          act[(size_t)(off + mrow) * IDIM + icol] = f2bf(sv);
        }
      }
    }
}

// ---------------- kernel: grouped GEMM down, atomic scatter into out ----------------
__global__ __launch_bounds__(256, 2) void k_down(
    const unsigned short* __restrict__ act, const float* __restrict__ w2,
    const int* __restrict__ counts, const int* __restrict__ offsets,
    const int* __restrict__ ltok, const float* __restrict__ lw,
    float* __restrict__ out)
{
  const int e   = blockIdx.z;
  const int cnt = counts[e];
  const int m0  = blockIdx.x * TM;
  if (m0 >= cnt) return;
  const int hb  = blockIdx.y * TN;
  const int off = offsets[e];

  __shared__ unsigned short As[TM * LDT];
  __shared__ unsigned short Ws[TN * LDT];

  const int tid  = threadIdx.x;
  const int lane = tid & 63, wid = tid >> 6;
  const int wm = wid & 1, wn = wid >> 1;
  const int quad = lane >> 4, l15 = lane & 15;

  const int ar = tid >> 3;
  const int ac = (tid & 7) * 8;
  const unsigned short* ap = act + (size_t)(off + m0 + ar) * IDIM + ac;
  const int wr = tid >> 2;
  const int wc = (tid & 3) * 16;
  const float* w2p = w2 + ((size_t)e * HID + hb + wr) * IDIM + wc;

  f32x4 acc[4][2];
#pragma unroll
  for (int mt = 0; mt < 4; ++mt)
#pragma unroll
    for (int nt = 0; nt < 2; ++nt) acc[mt][nt] = (f32x4)0.f;

  for (int kb = 0; kb < IDIM; kb += BK) {
    us8 av[4];
#pragma unroll
    for (int r4 = 0; r4 < 4; ++r4)
      av[r4] = *(const us8*)(ap + (size_t)r4 * 32 * IDIM + kb);
    float4 va = *(const float4*)(w2p + kb),     vb = *(const float4*)(w2p + kb + 4);
    float4 vc = *(const float4*)(w2p + kb + 8), vd = *(const float4*)(w2p + kb + 12);

    __syncthreads();
#pragma unroll
    for (int r4 = 0; r4 < 4; ++r4)
      *(us8*)&As[(ar + 32 * r4) * LDT + ac] = av[r4];
    {
      us8 q0, q1;
      q0[0]=f2bf(va.x); q0[1]=f2bf(va.y); q0[2]=f2bf(va.z); q0[3]=f2bf(va.w);
      q0[4]=f2bf(vb.x); q0[5]=f2bf(vb.y); q0[6]=f2bf(vb.z); q0[7]=f2bf(vb.w);
      q1[0]=f2bf(vc.x); q1[1]=f2bf(vc.y); q1[2]=f2bf(vc.z); q1[3]=f2bf(vc.w);
      q1[4]=f2bf(vd.x); q1[5]=f2bf(vd.y); q1[6]=f2bf(vd.z); q1[7]=f2bf(vd.w);
      *(us8*)&Ws[wr * LDT + wc] = q0;
      *(us8*)&Ws[wr * LDT + wc + 8] = q1;
    }
    __syncthreads();

#pragma unroll
    for (int ks = 0; ks < 2; ++ks) {
      bf16x8 af[4];
#pragma unroll
      for (int mt = 0; mt < 4; ++mt)
        af[mt] = *(const bf16x8*)&As[(wm * 64 + mt * 16 + l15) * LDT + ks * 32 + quad * 8];
      bf16x8 bf[2];
#pragma unroll
      for (int nt = 0; nt < 2; ++nt)
        bf[nt] = *(const bf16x8*)&Ws[(wn * 32 + nt * 16 + l15) * LDT + ks * 32 + quad * 8];
#pragma unroll
      for (int mt = 0; mt < 4; ++mt)
#pragma unroll
        for (int nt = 0; nt < 2; ++nt)
          acc[mt][nt] = __builtin_amdgcn_mfma_f32_16x16x32_bf16(af[mt], bf[nt], acc[mt][nt], 0, 0, 0);
    }
  }

#pragma unroll
  for (int mt = 0; mt < 4; ++mt) {
#pragma unroll
    for (int r = 0; r < 4; ++r) {
      int mrow = m0 + wm * 64 + mt * 16 + quad * 4 + r;
      if (mrow < cnt) {
        int tok   = ltok[e * T_TOK + mrow];
        float wgt = lw[e * T_TOK + mrow];
#pragma unroll
        for (int nt = 0; nt < 2; ++nt) {
          int col = hb + wn * 32 + nt * 16 + l15;
          atomicAdd(&out[(size_t)tok * HID + col], wgt * acc[mt][nt][r]);
        }
      }
    }
  }
}

// ---------------- kernel: add zero-expert contribution ----------------
__global__ void k_combine(const float* __restrict__ x, const float* __restrict__ zw,
                          float* __restrict__ out) {
  int i = blockIdx.x * 256 + threadIdx.x;     // float4 index
  float z = zw[i >> 9];                       // HID/4 = 512 float4 per token
  float4 xv = ((const float4*)x)[i];
  float4* op = (float4*)out + i;
  float4 ov = *op;
  ov.x = fmaf(z, xv.x, ov.x);
  ov.y = fmaf(z, xv.y, ov.y);
  ov.z = fmaf(z, xv.z, ov.z);
  ov.w = fmaf(z, xv.w, ov.w);
  *op = ov;
}

extern "C" void kernel_launch(void* const* d_in, const int* in_sizes, int n_in,
                              void* d_out, int out_size, void* d_ws, size_t ws_size,
                              hipStream_t stream) {
  const float* x  = (const float*)d_in[0];
  const float* rw = (const float*)d_in[1];
  const float* cb = (const float*)d_in[2];
  const float* w1 = (const float*)d_in[3];
  const float* w3 = (const float*)d_in[4];
  const float* w2 = (const float*)d_in[5];
  float* out = (float*)d_out;

  char* ws = (char*)d_ws;
  int*   counts  = (int*)(ws + 0);                 // 128 B (zeroed)
  int*   offsets = (int*)(ws + 4096);
  float* zw      = (float*)(ws + 8192);            // 16 KB
  int*   ltok    = (int*)(ws + (1 << 15));         // 512 KB
  float* lw      = (float*)(ws + (1 << 15) + (1 << 19)); // 512 KB
  unsigned short* xb  = (unsigned short*)(ws + (2u << 20));                      // 16 MB
  unsigned short* act = (unsigned short*)(ws + (2u << 20) + (size_t)T_TOK * HID * 2); // ~50.9 MB

  hipMemsetAsync(counts, 0, 4096, stream);
  hipMemsetAsync(out, 0, (size_t)out_size * sizeof(float), stream);

  k_cvt_x  <<<dim3(T_TOK * HID / (256 * 8)), dim3(256), 0, stream>>>(x, xb);
  k_router <<<dim3(T_TOK / 16),              dim3(256), 0, stream>>>(x, rw, cb, zw, counts, ltok, lw);
  k_scan   <<<dim3(1),                       dim3(64),  0, stream>>>(counts, offsets);
  k_gate_up<<<dim3(T_TOK / TM, IDIM / TN, NEXP), dim3(256), 0, stream>>>(xb, w1, w3, counts, offsets, ltok, act);
  k_down   <<<dim3(T_TOK / TM, HID / TN, NEXP),  dim3(256), 0, stream>>>(act, w2, counts, offsets, ltok, lw, out);
  k_combine<<<dim3(T_TOK * HID / (4 * 256)), dim3(256), 0, stream>>>(x, zw, out);
}

// Round 2
// 1582.415 us; speedup vs baseline: 2.3000x; 2.3000x over previous
//
#include <hip/hip_runtime.h>
#include <hip/hip_bf16.h>
#include <cstdint>
#include <cstddef>

#define T_TOK  4096
#define HID    2048
#define NEXP   32
#define NROUTE 48
#define IDIM   1024
#define TOPK   6
#define RSCALE 2.5f

// GEMM tiling
#define TM  128
#define TN  64
#define BK  64
#define LDT 88   // LDS row stride (bf16 elems): 64 + 24 pad, 16B aligned

typedef __attribute__((ext_vector_type(8))) __bf16 bf16x8;
typedef __attribute__((ext_vector_type(4))) float f32x4;
typedef __attribute__((ext_vector_type(8))) unsigned short us8;

static __device__ __forceinline__ unsigned short f2bf(float f) {
  unsigned u = __builtin_bit_cast(unsigned, f);
  u += 0x7fffu + ((u >> 16) & 1u);          // round-to-nearest-even
  return (unsigned short)(u >> 16);
}

// ---------------- kernel: x fp32 -> bf16 ----------------
__global__ void k_cvt_x(const float* __restrict__ x, unsigned short* __restrict__ xb) {
  int i = blockIdx.x * blockDim.x + threadIdx.x;   // one thread = 8 elems
  const float4* xv = (const float4*)x;
  float4 a = xv[2 * i], b = xv[2 * i + 1];
  us8 p;
  p[0] = f2bf(a.x); p[1] = f2bf(a.y); p[2] = f2bf(a.z); p[3] = f2bf(a.w);
  p[4] = f2bf(b.x); p[5] = f2bf(b.y); p[6] = f2bf(b.z); p[7] = f2bf(b.w);
  *(us8*)(xb + 8 * (size_t)i) = p;
}

// ---------------- kernel: router (fp32) + top-6 + expert lists ----------------
__global__ __launch_bounds__(256) void k_router(
    const float* __restrict__ x, const float* __restrict__ rw,
    const float* __restrict__ cb, float* __restrict__ zw_out,
    int* __restrict__ counts, int* __restrict__ ltok, float* __restrict__ lw)
{
  __shared__ float xs[16][132];
  __shared__ float wsm[48][132];
  __shared__ float sc[16][48];
  __shared__ float cbs[48];
  const int tid = threadIdx.x;
  const int t0 = blockIdx.x * 16;
  if (tid < NROUTE) cbs[tid] = cb[tid];
  const int tl = tid & 15, eg = tid >> 4;
  const int e0 = eg * 3;
  float a0 = 0.f, a1 = 0.f, a2 = 0.f;

  for (int hb = 0; hb < HID; hb += 128) {
    {
      int r = tid >> 4, c = (tid & 15) * 8;
      const float4* s = (const float4*)(x + (size_t)(t0 + r) * HID + hb + c);
      *(float4*)&xs[r][c]     = s[0];
      *(float4*)&xs[r][c + 4] = s[1];
    }
#pragma unroll
    for (int j = 0; j < 3; ++j) {
      int L = tid * 8 + j * 2048;
      int r = L >> 7, c = L & 127;
      const float4* s = (const float4*)(rw + (size_t)r * HID + hb + c);
      *(float4*)&wsm[r][c]     = s[0];
      *(float4*)&wsm[r][c + 4] = s[1];
    }
    __syncthreads();
#pragma unroll 8
    for (int h = 0; h < 128; h += 4) {
      float4 xv = *(const float4*)&xs[tl][h];
      float4 w0 = *(const float4*)&wsm[e0][h];
      float4 w1v = *(const float4*)&wsm[e0 + 1][h];
      float4 w2v = *(const float4*)&wsm[e0 + 2][h];
      a0 += xv.x * w0.x + xv.y * w0.y + xv.z * w0.z + xv.w * w0.w;
      a1 += xv.x * w1v.x + xv.y * w1v.y + xv.z * w1v.z + xv.w * w1v.w;
      a2 += xv.x * w2v.x + xv.y * w2v.y + xv.z * w2v.z + xv.w * w2v.w;
    }
    __syncthreads();
  }
  sc[tl][e0]     = 1.f / (1.f + expf(-a0));
  sc[tl][e0 + 1] = 1.f / (1.f + expf(-a1));
  sc[tl][e0 + 2] = 1.f / (1.f + expf(-a2));
  __syncthreads();

  if (tid < 16) {
    int t = t0 + tid;
    unsigned long long used = 0ull;
    float wsum = 0.f, zwv = 0.f;
    int   re[TOPK];  float rwt[TOPK];  int nr = 0;
#pragma unroll
    for (int k = 0; k < TOPK; ++k) {
      float best = -1e30f; int bi = 0;
      for (int e = 0; e < NROUTE; ++e) {
        if ((used >> e) & 1ull) continue;
        float v = sc[tid][e] + cbs[e];
        if (v > best) { best = v; bi = e; }   // strict > keeps lowest index on ties (lax.top_k)
      }
      used |= 1ull << bi;
      float w = sc[tid][bi];
      wsum += w;
      if (bi >= NEXP) zwv += w;
      else { re[nr] = bi; rwt[nr] = w; ++nr; }
    }
    float scale = RSCALE / wsum;
    zw_out[t] = zwv * scale;
    for (int j = 0; j < nr; ++j) {
      int e = re[j];
      int p = atomicAdd(&counts[e], 1);
      ltok[e * T_TOK + p] = t;
      lw[e * T_TOK + p]   = rwt[j] * scale;
    }
  }
}

// ---------------- kernel: exclusive scan of counts ----------------
__global__ void k_scan(const int* __restrict__ counts, int* __restrict__ offsets) {
  if (threadIdx.x == 0) {
    int o = 0;
    for (int e = 0; e < NEXP; ++e) { offsets[e] = o; o += counts[e]; }
  }
}

// ---------------- kernel: out = x * zero_weight (also initializes out for atomics) ----
__global__ void k_init_out(const float* __restrict__ x, const float* __restrict__ zw,
                           float* __restrict__ out) {
  int i = blockIdx.x * 256 + threadIdx.x;     // float4 index
  float z = zw[i >> 9];                       // HID/4 = 512 float4 per token
  float4 xv = ((const float4*)x)[i];
  float4 ov;
  ov.x = z * xv.x; ov.y = z * xv.y; ov.z = z * xv.z; ov.w = z * xv.w;
  ((float4*)out)[i] = ov;
}

// ---------------- kernel: grouped GEMM gate+up + SiLU, act out (bf16) ----------------
// One block per (expert, n-tile of 64 I-cols); loops over the expert's m-tiles.
// Weight K-strip is re-read per m-tile by the SAME block -> L2 hits; HBM reads weights once.
__global__ __launch_bounds__(256, 3) void k_gate_up(
    const unsigned short* __restrict__ xb, const float* __restrict__ w1,
    const float* __restrict__ w3, const int* __restrict__ counts,
    const int* __restrict__ offsets, const int* __restrict__ ltok,
    unsigned short* __restrict__ act)
{
  const int g   = blockIdx.x;          // 0..511
  const int e   = g >> 4;
  const int nb  = (g & 15) * TN;
  const int cnt = counts[e];
  if (cnt == 0) return;
  const int off = offsets[e];
  const int mt  = (cnt + TM - 1) / TM;

  __shared__ unsigned short As[TM * LDT];
  __shared__ unsigned short W1s[TN * LDT];
  __shared__ unsigned short W3s[TN * LDT];

  const int tid  = threadIdx.x;
  const int lane = tid & 63, wid = tid >> 6;
  const int wm = wid & 1, wn = wid >> 1;
  const int quad = lane >> 4, l15 = lane & 15;

  // A staging map: 8 threads per row, 4 rows per thread
  const int ar = tid >> 3;            // 0..31
  const int ac = (tid & 7) * 8;       // 0..56
  // W staging map: 4 threads per row (16 fp32 each)
  const int wr = tid >> 2;            // 0..63
  const int wc = (tid & 3) * 16;      // 0..48
  const float* w1p = w1 + ((size_t)e * IDIM + (nb + wr)) * HID + wc;
  const float* w3p = w3 + ((size_t)e * IDIM + (nb + wr)) * HID + wc;

  us8    av[4];
  float4 p1[4], p3[4];
  int    tokr[4];

  auto loadA = [&](int kb) {
#pragma unroll
    for (int r4 = 0; r4 < 4; ++r4)
      av[r4] = *(const us8*)(xb + (size_t)tokr[r4] * HID + kb + ac);
  };
  auto loadW = [&](int kb) {
#pragma unroll
    for (int j = 0; j < 4; ++j) {
      p1[j] = *(const float4*)(w1p + kb + 4 * j);
      p3[j] = *(const float4*)(w3p + kb + 4 * j);
    }
  };

  for (int mi = 0; mi < mt; ++mi) {
    const int m0 = mi * TM;
#pragma unroll
    for (int r4 = 0; r4 < 4; ++r4) {
      int mr = m0 + ar + 32 * r4;
      tokr[r4] = (mr < cnt) ? ltok[e * T_TOK + mr] : 0;
    }
    loadA(0);
    loadW(0);

    f32x4 accg[4][2], accu[4][2];
#pragma unroll
    for (int mtt = 0; mtt < 4; ++mtt)
#pragma unroll
      for (int nt = 0; nt < 2; ++nt) { accg[mtt][nt] = (f32x4)0.f; accu[mtt][nt] = (f32x4)0.f; }

    for (int kb = 0; kb < HID; kb += BK) {
      __syncthreads();
#pragma unroll
      for (int r4 = 0; r4 < 4; ++r4)
        *(us8*)&As[(ar + 32 * r4) * LDT + ac] = av[r4];
      {
        us8 q0, q1;
        q0[0]=f2bf(p1[0].x); q0[1]=f2bf(p1[0].y); q0[2]=f2bf(p1[0].z); q0[3]=f2bf(p1[0].w);
        q0[4]=f2bf(p1[1].x); q0[5]=f2bf(p1[1].y); q0[6]=f2bf(p1[1].z); q0[7]=f2bf(p1[1].w);
        q1[0]=f2bf(p1[2].x); q1[1]=f2bf(p1[2].y); q1[2]=f2bf(p1[2].z); q1[3]=f2bf(p1[2].w);
        q1[4]=f2bf(p1[3].x); q1[5]=f2bf(p1[3].y); q1[6]=f2bf(p1[3].z); q1[7]=f2bf(p1[3].w);
        *(us8*)&W1s[wr * LDT + wc] = q0;
        *(us8*)&W1s[wr * LDT + wc + 8] = q1;
        q0[0]=f2bf(p3[0].x); q0[1]=f2bf(p3[0].y); q0[2]=f2bf(p3[0].z); q0[3]=f2bf(p3[0].w);
        q0[4]=f2bf(p3[1].x); q0[5]=f2bf(p3[1].y); q0[6]=f2bf(p3[1].z); q0[7]=f2bf(p3[1].w);
        q1[0]=f2bf(p3[2].x); q1[1]=f2bf(p3[2].y); q1[2]=f2bf(p3[2].z); q1[3]=f2bf(p3[2].w);
        q1[4]=f2bf(p3[3].x); q1[5]=f2bf(p3[3].y); q1[6]=f2bf(p3[3].z); q1[7]=f2bf(p3[3].w);
        *(us8*)&W3s[wr * LDT + wc] = q0;
        *(us8*)&W3s[wr * LDT + wc + 8] = q1;
      }
      __syncthreads();

      // prefetch next K-chunk while MFMAs run (latency hidden behind compute + next barrier)
      if (kb + BK < HID) { loadA(kb + BK); loadW(kb + BK); }

#pragma unroll
      for (int ks = 0; ks < 2; ++ks) {
        bf16x8 af[4];
#pragma unroll
        for (int mtt = 0; mtt < 4; ++mtt)
          af[mtt] = *(const bf16x8*)&As[(wm * 64 + mtt * 16 + l15) * LDT + ks * 32 + quad * 8];
        bf16x8 b1f[2], b3f[2];
#pragma unroll
        for (int nt = 0; nt < 2; ++nt) {
          b1f[nt] = *(const bf16x8*)&W1s[(wn * 32 + nt * 16 + l15) * LDT + ks * 32 + quad * 8];
          b3f[nt] = *(const bf16x8*)&W3s[(wn * 32 + nt * 16 + l15) * LDT + ks * 32 + quad * 8];
        }
#pragma unroll
        for (int mtt = 0; mtt < 4; ++mtt)
#pragma unroll
          for (int nt = 0; nt < 2; ++nt) {
            accg[mtt][nt] = __builtin_amdgcn_mfma_f32_16x16x32_bf16(af[mtt], b1f[nt], accg[mtt][nt], 0, 0, 0);
            accu[mtt][nt] = __builtin_amdgcn_mfma_f32_16x16x32_bf16(af[mtt], b3f[nt], accu[mtt][nt], 0, 0, 0);
          }
      }
    }

#pragma unroll
    for (int mtt = 0; mtt < 4; ++mtt)
#pragma unroll
      for (int nt = 0; nt < 2; ++nt) {
        int icol = nb + wn * 32 + nt * 16 + l15;
#pragma unroll
        for (int r = 0; r < 4; ++r) {
          int mrow = m0 + wm * 64 + mtt * 16 + quad * 4 + r;
          if (mrow < cnt) {
            float gg = accg[mtt][nt][r], u = accu[mtt][nt][r];
            float sv = gg / (1.f + expf(-gg)) * u;      // silu(g)*u
            act[(size_t)(off + mrow) * IDIM + icol] = f2bf(sv);
          }
        }
      }
  }
}

// ---------------- kernel: grouped GEMM down, atomic scatter into out ----------------
// One block per (expert, 64-col H-tile); loops over the expert's m-tiles.
__global__ __launch_bounds__(256, 3) void k_down(
    const unsigned short* __restrict__ act, const float* __restrict__ w2,
    const int* __restrict__ counts, const int* __restrict__ offsets,
    const int* __restrict__ ltok, const float* __restrict__ lw,
    float* __restrict__ out)
{
  const int g   = blockIdx.x;          // 0..1023
  const int e   = g >> 5;
  const int hb  = (g & 31) * TN;
  const int cnt = counts[e];
  if (cnt == 0) return;
  const int off = offsets[e];
  const int mt  = (cnt + TM - 1) / TM;

  __shared__ unsigned short As[TM * LDT];
  __shared__ unsigned short Ws[TN * LDT];

  const int tid  = threadIdx.x;
  const int lane = tid & 63, wid = tid >> 6;
  const int wm = wid & 1, wn = wid >> 1;
  const int quad = lane >> 4, l15 = lane & 15;

  const int ar = tid >> 3;
  const int ac = (tid & 7) * 8;
  const int wr = tid >> 2;
  const int wc = (tid & 3) * 16;
  const float* w2p = w2 + ((size_t)e * HID + hb + wr) * IDIM + wc;

  us8    av[4];
  float4 pw[4];

  auto loadW = [&](int kb) {
#pragma unroll
    for (int j = 0; j < 4; ++j) pw[j] = *(const float4*)(w2p + kb + 4 * j);
  };

  for (int mi = 0; mi < mt; ++mi) {
    const int m0 = mi * TM;
    const unsigned short* ap = act + (size_t)(off + m0 + ar) * IDIM + ac;

    auto loadA = [&](int kb) {
#pragma unroll
      for (int r4 = 0; r4 < 4; ++r4)
        av[r4] = *(const us8*)(ap + (size_t)r4 * 32 * IDIM + kb);
    };
    loadA(0);
    loadW(0);

    f32x4 acc[4][2];
#pragma unroll
    for (int mtt = 0; mtt < 4; ++mtt)
#pragma unroll
      for (int nt = 0; nt < 2; ++nt) acc[mtt][nt] = (f32x4)0.f;

    for (int kb = 0; kb < IDIM; kb += BK) {
      __syncthreads();
#pragma unroll
      for (int r4 = 0; r4 < 4; ++r4)
        *(us8*)&As[(ar + 32 * r4) * LDT + ac] = av[r4];
      {
        us8 q0, q1;
        q0[0]=f2bf(pw[0].x); q0[1]=f2bf(pw[0].y); q0[2]=f2bf(pw[0].z); q0[3]=f2bf(pw[0].w);
        q0[4]=f2bf(pw[1].x); q0[5]=f2bf(pw[1].y); q0[6]=f2bf(pw[1].z); q0[7]=f2bf(pw[1].w);
        q1[0]=f2bf(pw[2].x); q1[1]=f2bf(pw[2].y); q1[2]=f2bf(pw[2].z); q1[3]=f2bf(pw[2].w);
        q1[4]=f2bf(pw[3].x); q1[5]=f2bf(pw[3].y); q1[6]=f2bf(pw[3].z); q1[7]=f2bf(pw[3].w);
        *(us8*)&Ws[wr * LDT + wc] = q0;
        *(us8*)&Ws[wr * LDT + wc + 8] = q1;
      }
      __syncthreads();

      if (kb + BK < IDIM) { loadA(kb + BK); loadW(kb + BK); }

#pragma unroll
      for (int ks = 0; ks < 2; ++ks) {
        bf16x8 af[4];
#pragma unroll
        for (int mtt = 0; mtt < 4; ++mtt)
          af[mtt] = *(const bf16x8*)&As[(wm * 64 + mtt * 16 + l15) * LDT + ks * 32 + quad * 8];
        bf16x8 bf[2];
#pragma unroll
        for (int nt = 0; nt < 2; ++nt)
          bf[nt] = *(const bf16x8*)&Ws[(wn * 32 + nt * 16 + l15) * LDT + ks * 32 + quad * 8];
#pragma unroll
        for (int mtt = 0; mtt < 4; ++mtt)
#pragma unroll
          for (int nt = 0; nt < 2; ++nt)
            acc[mtt][nt] = __builtin_amdgcn_mfma_f32_16x16x32_bf16(af[mtt], bf[nt], acc[mtt][nt], 0, 0, 0);
      }
    }

#pragma unroll
    for (int mtt = 0; mtt < 4; ++mtt) {
#pragma unroll
      for (int r = 0; r < 4; ++r) {
        int mrow = m0 + wm * 64 + mtt * 16 + quad * 4 + r;
        if (mrow < cnt) {
          int tok   = ltok[e * T_TOK + mrow];
          float wgt = lw[e * T_TOK + mrow];
#pragma unroll
          for (int nt = 0; nt < 2; ++nt) {
            int col = hb + wn * 32 + nt * 16 + l15;
            atomicAdd(&out[(size_t)tok * HID + col], wgt * acc[mtt][nt][r]);
          }
        }
      }
    }
  }
}

extern "C" void kernel_launch(void* const* d_in, const int* in_sizes, int n_in,
                              void* d_out, int out_size, void* d_ws, size_t ws_size,
                              hipStream_t stream) {
  const float* x  = (const float*)d_in[0];
  const float* rw = (const float*)d_in[1];
  const float* cb = (const float*)d_in[2];
  const float* w1 = (const float*)d_in[3];
  const float* w3 = (const float*)d_in[4];
  const float* w2 = (const float*)d_in[5];
  float* out = (float*)d_out;

  char* ws = (char*)d_ws;
  int*   counts  = (int*)(ws + 0);                 // zeroed below
  int*   offsets = (int*)(ws + 4096);
  float* zw      = (float*)(ws + 8192);            // 16 KB
  int*   ltok    = (int*)(ws + (1 << 15));         // 512 KB
  float* lw      = (float*)(ws + (1 << 15) + (1 << 19)); // 512 KB
  unsigned short* xb  = (unsigned short*)(ws + (2u << 20));                      // 16 MB
  unsigned short* act = (unsigned short*)(ws + (2u << 20) + (size_t)T_TOK * HID * 2); // ~50.3 MB

  hipMemsetAsync(counts, 0, 4096, stream);

  k_cvt_x   <<<dim3(T_TOK * HID / (256 * 8)), dim3(256), 0, stream>>>(x, xb);
  k_router  <<<dim3(T_TOK / 16),              dim3(256), 0, stream>>>(x, rw, cb, zw, counts, ltok, lw);
  k_scan    <<<dim3(1),                       dim3(64),  0, stream>>>(counts, offsets);
  k_init_out<<<dim3(T_TOK * HID / (4 * 256)), dim3(256), 0, stream>>>(x, zw, out);
  k_gate_up <<<dim3(NEXP * (IDIM / TN)),      dim3(256), 0, stream>>>(xb, w1, w3, counts, offsets, ltok, act);
  k_down    <<<dim3(NEXP * (HID / TN)),       dim3(256), 0, stream>>>(act, w2, counts, offsets, ltok, lw, out);
}